// Round 12
// baseline (256.200 us; speedup 1.0000x reference)
//
#include <hip/hip_runtime.h>

// ---------------- static problem config ----------------
#define LQN   13294
#define NBAT  2
#define MROWS (NBAT * LQN)   // 26588
#define CCH   256
#define NHEAD 8
#define DHEAD 32
#define NLVL  4
#define NPT   4
#define DFF   2048

typedef short short8 __attribute__((ext_vector_type(8)));
typedef float f32x4 __attribute__((ext_vector_type(4)));
typedef unsigned short u16;
typedef u16 u16x4 __attribute__((ext_vector_type(4)));
typedef unsigned int u32;
typedef u32 u32x4 __attribute__((ext_vector_type(4)));

__device__ __forceinline__ u16 f2bf(float f) {
  unsigned int u = __builtin_bit_cast(unsigned int, f);
  u += 0x7fffu + ((u >> 16) & 1u);   // RNE
  return (u16)(u >> 16);
}
__device__ __forceinline__ float bf2f(u16 s) {
  unsigned int u = ((unsigned int)s) << 16;
  return __builtin_bit_cast(float, u);
}
__device__ __forceinline__ void async16(const void* g, void* l) {
  __builtin_amdgcn_global_load_lds(
      (const __attribute__((address_space(1))) void*)g,
      (__attribute__((address_space(3))) void*)l, 16, 0, 0);
}

// ---------------- dual GEMM: value-proj (bn<2, bf16 out) + off/attn-proj (bn>=2, f32) ----------------
__global__ __launch_bounds__(256, 2)
void gemm_dual(const u16* __restrict__ A0, const u16* __restrict__ BT0,
               const float* __restrict__ bias0, u16* __restrict__ C0,
               const u16* __restrict__ A1, const u16* __restrict__ BT1,
               const float* __restrict__ bias1, float* __restrict__ C1)
{
  __shared__ u16 As[2][128 * 64];
  __shared__ u16 Bs[2][128 * 64];
  const int t    = threadIdx.x;
  const int lane = t & 63;
  const int wid  = t >> 6;
  const int wm   = wid >> 1, wn = wid & 1;
  const int bm   = blockIdx.x;
  const int bnG  = blockIdx.y;
  const bool first = bnG < 2;
  const u16* A    = first ? A0 : A1;
  const u16* BT   = first ? BT0 : BT1;
  const float* bias = first ? bias0 : bias1;
  const int  bn   = first ? bnG : bnG - 2;
  const int l15  = lane & 15;
  const int kq   = lane >> 4;

  f32x4 acc[4][4];
#pragma unroll
  for (int m = 0; m < 4; ++m)
#pragma unroll
    for (int n = 0; n < 4; ++n) acc[m][n] = (f32x4)0.0f;

  auto stage = [&](int buf, int kt) {
#pragma unroll
    for (int i = 0; i < 4; ++i) {
      const int c   = i * 256 + t;
      const int row = c >> 3;
      const int kg  = (c & 7) ^ (row & 7);
      int ar = bm * 128 + row; ar = ar < MROWS ? ar : MROWS - 1;
      async16(&A[(size_t)ar * 256 + kt + kg * 8], &As[buf][c * 8]);
      const int br = bn * 128 + row;
      async16(&BT[(size_t)br * 256 + kt + kg * 8], &Bs[buf][c * 8]);
    }
  };

  stage(0, 0);
  __syncthreads();
  int cur = 0;

  for (int kt = 0; kt < 256; kt += 64) {
    if (kt + 64 < 256) stage(cur ^ 1, kt + 64);

#pragma unroll
    for (int kk = 0; kk < 2; ++kk) {
      short8 af[4], bfr[4];
#pragma unroll
      for (int m = 0; m < 4; ++m) {
        const int row = wm * 64 + m * 16 + l15;
        const int xb  = (kk * 64 + kq * 16) ^ ((row & 7) << 4);
        af[m] = *(const short8*)((const char*)&As[cur][0] + row * 128 + xb);
      }
#pragma unroll
      for (int n = 0; n < 4; ++n) {
        const int col = wn * 64 + n * 16 + l15;
        const int xb  = (kk * 64 + kq * 16) ^ ((col & 7) << 4);
        bfr[n] = *(const short8*)((const char*)&Bs[cur][0] + col * 128 + xb);
      }
#pragma unroll
      for (int m = 0; m < 4; ++m)
#pragma unroll
        for (int n = 0; n < 4; ++n)
          acc[m][n] = __builtin_amdgcn_mfma_f32_16x16x32_bf16(af[m], bfr[n], acc[m][n], 0, 0, 0);
    }

    __syncthreads();
    cur ^= 1;
  }

  const int crow0 = bm * 128 + wm * 64;
  const int ccol0 = bn * 128 + wn * 64;
#pragma unroll
  for (int n = 0; n < 4; ++n) {
    int col = ccol0 + n * 16 + l15;
    float bv = bias[col];
#pragma unroll
    for (int m = 0; m < 4; ++m) {
      int rbase = crow0 + m * 16 + kq * 4;
#pragma unroll
      for (int j = 0; j < 4; ++j) {
        int row = rbase + j;
        if (row < MROWS) {
          float v = acc[m][n][j] + bv;
          if (first) C0[(size_t)row * 256 + col] = f2bf(v);
          else       C1[(size_t)row * 384 + col] = v;
        }
      }
    }
  }
}

// ---------------- out-proj + LN1 fused ----------------
__global__ __launch_bounds__(512, 1)
void outproj_ln1(const u16* __restrict__ src2_bf, const u16* __restrict__ WT_out,
                 const float* __restrict__ b_out, const float* __restrict__ src,
                 const float* __restrict__ g1, const float* __restrict__ be1,
                 float* __restrict__ x_f32, u16* __restrict__ x_bf)
{
  extern __shared__ char smem[];
  char* As0 = smem;                 // [128][128B]
  char* As1 = smem + 16384;
  char* Bs0 = smem + 32768;         // [256][128B]
  char* Bs1 = smem + 65536;
  float2* red = (float2*)(smem + 98304);   // [128][4]

  const int t    = threadIdx.x;
  const int lane = t & 63;
  const int wid  = t >> 6;
  const int wm   = wid >> 2, wn = wid & 3;   // 2x4 waves, tile 64x64
  const int l15  = lane & 15;
  const int kq   = lane >> 4;
  const int bm   = blockIdx.x;

  auto stage = [&](char* Abuf, char* Bbuf, int kt) {
#pragma unroll
    for (int i = 0; i < 2; ++i) {
      const int c   = i * 512 + t;
      const int row = c >> 3;
      const int kg  = (c & 7) ^ (row & 7);
      int ar = bm * 128 + row; ar = ar < MROWS ? ar : MROWS - 1;
      async16(&src2_bf[(size_t)ar * 256 + kt + kg * 8], Abuf + c * 16);
    }
#pragma unroll
    for (int i = 0; i < 4; ++i) {
      const int c   = i * 512 + t;
      const int row = c >> 3;
      const int kg  = (c & 7) ^ (row & 7);
      async16(&WT_out[(size_t)row * 256 + kt + kg * 8], Bbuf + c * 16);
    }
  };

  f32x4 acc[4][4];
#pragma unroll
  for (int m = 0; m < 4; ++m)
#pragma unroll
    for (int n = 0; n < 4; ++n) acc[m][n] = (f32x4)0.0f;

  stage(As0, Bs0, 0);
  __syncthreads();

  for (int kt = 0; kt < 256; kt += 64) {
    const int cur = (kt >> 6) & 1;
    char* Ause = cur ? As1 : As0;
    char* Buse = cur ? Bs1 : Bs0;
    if (kt + 64 < 256) stage(cur ? As0 : As1, cur ? Bs0 : Bs1, kt + 64);

#pragma unroll
    for (int kk = 0; kk < 2; ++kk) {
      short8 af[4], bfr[4];
#pragma unroll
      for (int m = 0; m < 4; ++m) {
        const int row = wm * 64 + m * 16 + l15;
        const int xb  = (kk * 64 + kq * 16) ^ ((row & 7) << 4);
        af[m] = *(const short8*)(Ause + row * 128 + xb);
      }
#pragma unroll
      for (int n = 0; n < 4; ++n) {
        const int col = wn * 64 + n * 16 + l15;
        const int xb  = (kk * 64 + kq * 16) ^ ((col & 7) << 4);
        bfr[n] = *(const short8*)(Buse + col * 128 + xb);
      }
#pragma unroll
      for (int m = 0; m < 4; ++m)
#pragma unroll
        for (int n = 0; n < 4; ++n)
          acc[m][n] = __builtin_amdgcn_mfma_f32_16x16x32_bf16(af[m], bfr[n], acc[m][n], 0, 0, 0);
    }
    __syncthreads();
  }

  // ---- epilogue: v = acc + b_out + src ; LN1 ; write x_f32, x_bf ----
#pragma unroll
  for (int n = 0; n < 4; ++n) {
    const int col = wn * 64 + n * 16 + l15;
    const float bv = b_out[col];
#pragma unroll
    for (int m = 0; m < 4; ++m)
#pragma unroll
      for (int j = 0; j < 4; ++j) {
        int row = bm * 128 + wm * 64 + m * 16 + kq * 4 + j;
        row = row < MROWS ? row : MROWS - 1;
        acc[m][n][j] += bv + src[(size_t)row * 256 + col];
      }
  }
  float s1[4][4], s2[4][4];
#pragma unroll
  for (int m = 0; m < 4; ++m)
#pragma unroll
    for (int j = 0; j < 4; ++j) {
      float a = 0.f, b = 0.f;
#pragma unroll
      for (int n = 0; n < 4; ++n) { const float v = acc[m][n][j]; a += v; b += v * v; }
      s1[m][j] = a; s2[m][j] = b;
    }
#pragma unroll
  for (int o = 1; o < 16; o <<= 1)
#pragma unroll
    for (int m = 0; m < 4; ++m)
#pragma unroll
      for (int j = 0; j < 4; ++j) {
        s1[m][j] += __shfl_xor(s1[m][j], o, 64);
        s2[m][j] += __shfl_xor(s2[m][j], o, 64);
      }
  if (l15 == 0)
#pragma unroll
    for (int m = 0; m < 4; ++m)
#pragma unroll
      for (int j = 0; j < 4; ++j)
        red[(wm * 64 + m * 16 + kq * 4 + j) * 4 + wn] = make_float2(s1[m][j], s2[m][j]);
  __syncthreads();
  float mean[4][4], rstd[4][4];
#pragma unroll
  for (int m = 0; m < 4; ++m)
#pragma unroll
    for (int j = 0; j < 4; ++j) {
      const int rl = wm * 64 + m * 16 + kq * 4 + j;
      float a = 0.f, b = 0.f;
#pragma unroll
      for (int w = 0; w < 4; ++w) { const float2 r = red[rl * 4 + w]; a += r.x; b += r.y; }
      const float mu = a * (1.0f / 256.0f);
      mean[m][j] = mu;
      rstd[m][j] = rsqrtf(b * (1.0f / 256.0f) - mu * mu + 1e-5f);
    }
#pragma unroll
  for (int n = 0; n < 4; ++n) {
    const int col = wn * 64 + n * 16 + l15;
    const float gg = g1[col], bb = be1[col];
#pragma unroll
    for (int m = 0; m < 4; ++m)
#pragma unroll
      for (int j = 0; j < 4; ++j) {
        const int row = bm * 128 + wm * 64 + m * 16 + kq * 4 + j;
        if (row < MROWS) {
          const float y = (acc[m][n][j] - mean[m][j]) * rstd[m][j] * gg + bb;
          x_f32[(size_t)row * 256 + col] = y;
          x_bf[(size_t)row * 256 + col] = f2bf(y);
        }
      }
  }
}

// ---------------- fused FFN + LN2 (v4 + transposed b64 ps writes) ----------------
// 1024 threads, 16 waves. ps writes: in-register 4x4 lane transpose (shfl_xor
// dist 1,2) so each lane stores 1 row x 4 consecutive cols as ONE ds_write_b64
// (was 8 scalar ds_write_b16 with 8.5M bank conflicts). PV reads unchanged.
__global__ __launch_bounds__(1024, 2)
void ffn_ln2(const u16* __restrict__ x_bf, const u16* __restrict__ W1T,
             const u16* __restrict__ W2T, const float* __restrict__ b1,
             const float* __restrict__ b2, const float* __restrict__ x_f32,
             const float* __restrict__ g2, const float* __restrict__ be2,
             float* __restrict__ out)
{
  extern __shared__ char smem[];
  u16*  w1s = (u16*)(smem);            // [2][64][256]
  u16*  w2s = (u16*)(smem + 65536);    // [2][256][64]
  char* ps  = smem + 131072;           // [128][144B]
  float2* red = (float2*)(smem + 149504);  // [128][4]

  const int t    = threadIdx.x;
  const int lane = t & 63;
  const int wid  = t >> 6;             // 0..15
  const int l15  = lane & 15;
  const int kq   = lane >> 4;
  const int bm   = blockIdx.x;
  const int pwm  = wid >> 1, pwn = wid & 1;   // P: 8x2, tile 16x32
  const int vwm  = wid >> 2, vwn = wid & 3;   // PV: 4x4, tile 32x64

  short8 xr[8];
  {
    int ar = bm * 128 + pwm * 16 + l15;
    ar = ar < MROWS ? ar : MROWS - 1;
    const char* xb = (const char*)x_bf + (size_t)ar * 512 + kq * 16;
#pragma unroll
    for (int ks = 0; ks < 8; ++ks) xr[ks] = *(const short8*)(xb + ks * 64);
  }

  auto stage = [&](int buf, int it) {
#pragma unroll
    for (int i = 0; i < 2; ++i) {
      const int c  = i * 1024 + t;
      const int r1 = c >> 5;
      const int k1 = ((c & 31) ^ (r1 & 7)) * 8;
      async16(&W1T[(size_t)(it * 64 + r1) * 256 + k1], &w1s[buf * 16384 + c * 8]);
      const int r2 = c >> 3;
      const int k2 = ((c & 7) ^ (r2 & 7)) * 8;
      async16(&W2T[(size_t)r2 * 2048 + it * 64 + k2], &w2s[buf * 16384 + c * 8]);
    }
  };

  f32x4 acc[2][4];
#pragma unroll
  for (int m = 0; m < 2; ++m)
#pragma unroll
    for (int n = 0; n < 4; ++n) acc[m][n] = (f32x4)0.0f;

  stage(0, 0);
  __syncthreads();

  for (int it = 0; it < 32; ++it) {
    const int cur = it & 1;
    if (it < 31) stage(cur ^ 1, it + 1);

    f32x4 p[2];
    p[0] = (f32x4)0.0f; p[1] = (f32x4)0.0f;
#pragma unroll
    for (int ks = 0; ks < 8; ++ks) {
#pragma unroll
      for (int n = 0; n < 2; ++n) {
        const int wrow = pwn * 32 + n * 16 + l15;
        const int xb   = (((ks * 4 + kq) ^ (wrow & 7)) << 4);
        const short8 bfr = *(const short8*)((const char*)&w1s[cur * 16384] + wrow * 512 + xb);
        p[n] = __builtin_amdgcn_mfma_f32_16x16x32_bf16(xr[ks], bfr, p[n], 0, 0, 0);
      }
    }

    // ---- bias + relu, 4x4 lane transpose, ONE b64 store per n ----
#pragma unroll
    for (int n = 0; n < 2; ++n) {
      const int col = pwn * 32 + n * 16 + l15;
      const float bv = b1[it * 64 + col];
      f32x4 v;
#pragma unroll
      for (int j = 0; j < 4; ++j) v[j] = fmaxf(p[n][j] + bv, 0.0f);
      // transpose among lanes 4a..4a+3 (i = lane&3): out_i[j] = in_j[i]
      {
        f32x4 tv, nv;
#pragma unroll
        for (int j = 0; j < 4; ++j) tv[j] = __shfl_xor(v[j], 1, 64);
        const bool odd = (lane & 1) != 0;
        nv[0] = odd ? tv[1] : v[0];
        nv[1] = odd ? v[1]  : tv[0];
        nv[2] = odd ? tv[3] : v[2];
        nv[3] = odd ? v[3]  : tv[2];
#pragma unroll
        for (int j = 0; j < 4; ++j) tv[j] = __shfl_xor(nv[j], 2, 64);
        const bool hi = (lane & 2) != 0;
        v[0] = hi ? tv[2] : nv[0];
        v[1] = hi ? tv[3] : nv[1];
        v[2] = hi ? nv[2] : tv[0];
        v[3] = hi ? nv[3] : tv[1];
      }
      const int prow = pwm * 16 + kq * 4 + (lane & 3);
      const int c0   = pwn * 32 + n * 16 + (l15 & ~3);
      unsigned long long w64 = (unsigned long long)f2bf(v[0])
        | ((unsigned long long)f2bf(v[1]) << 16)
        | ((unsigned long long)f2bf(v[2]) << 32)
        | ((unsigned long long)f2bf(v[3]) << 48);
      *(unsigned long long*)(ps + prow * 144 + c0 * 2) = w64;
    }
    __syncthreads();

#pragma unroll
    for (int kk = 0; kk < 2; ++kk) {
      short8 paf[2];
#pragma unroll
      for (int m = 0; m < 2; ++m) {
        const int arow = vwm * 32 + m * 16 + l15;
        paf[m] = *(const short8*)(ps + arow * 144 + (kk * 4 + kq) * 16);
      }
#pragma unroll
      for (int n = 0; n < 4; ++n) {
        const int brow = vwn * 64 + n * 16 + l15;
        const int xb   = (((kk * 4 + kq) ^ (brow & 7)) << 4);
        const short8 bfr = *(const short8*)((const char*)&w2s[cur * 16384] + brow * 128 + xb);
#pragma unroll
        for (int m = 0; m < 2; ++m)
          acc[m][n] = __builtin_amdgcn_mfma_f32_16x16x32_bf16(paf[m], bfr, acc[m][n], 0, 0, 0);
      }
    }
    __syncthreads();
  }

  // ---- epilogue: v = acc + b2 + x ; LN2 ; write d_out ----
#pragma unroll
  for (int n = 0; n < 4; ++n) {
    const int col = vwn * 64 + n * 16 + l15;
    const float bv = b2[col];
#pragma unroll
    for (int m = 0; m < 2; ++m)
#pragma unroll
      for (int j = 0; j < 4; ++j) {
        int row = bm * 128 + vwm * 32 + m * 16 + kq * 4 + j;
        row = row < MROWS ? row : MROWS - 1;
        acc[m][n][j] += bv + x_f32[(size_t)row * 256 + col];
      }
  }
  float s1[2][4], s2[2][4];
#pragma unroll
  for (int m = 0; m < 2; ++m)
#pragma unroll
    for (int j = 0; j < 4; ++j) {
      float a = 0.f, b = 0.f;
#pragma unroll
      for (int n = 0; n < 4; ++n) { const float v = acc[m][n][j]; a += v; b += v * v; }
      s1[m][j] = a; s2[m][j] = b;
    }
#pragma unroll
  for (int o = 1; o < 16; o <<= 1)
#pragma unroll
    for (int m = 0; m < 2; ++m)
#pragma unroll
      for (int j = 0; j < 4; ++j) {
        s1[m][j] += __shfl_xor(s1[m][j], o, 64);
        s2[m][j] += __shfl_xor(s2[m][j], o, 64);
      }
  if (l15 == 0)
#pragma unroll
    for (int m = 0; m < 2; ++m)
#pragma unroll
      for (int j = 0; j < 4; ++j)
        red[(vwm * 32 + m * 16 + kq * 4 + j) * 4 + vwn] = make_float2(s1[m][j], s2[m][j]);
  __syncthreads();
  float mean[2][4], rstd[2][4];
#pragma unroll
  for (int m = 0; m < 2; ++m)
#pragma unroll
    for (int j = 0; j < 4; ++j) {
      const int rl = vwm * 32 + m * 16 + kq * 4 + j;
      float a = 0.f, b = 0.f;
#pragma unroll
      for (int w = 0; w < 4; ++w) { const float2 r = red[rl * 4 + w]; a += r.x; b += r.y; }
      const float mu = a * (1.0f / 256.0f);
      mean[m][j] = mu;
      rstd[m][j] = rsqrtf(b * (1.0f / 256.0f) - mu * mu + 1e-5f);
    }
#pragma unroll
  for (int n = 0; n < 4; ++n) {
    const int col = vwn * 64 + n * 16 + l15;
    const float gg = g2[col], bb = be2[col];
#pragma unroll
    for (int m = 0; m < 2; ++m)
#pragma unroll
      for (int j = 0; j < 4; ++j) {
        const int row = bm * 128 + vwm * 32 + m * 16 + kq * 4 + j;
        if (row < MROWS)
          out[(size_t)row * 256 + col] = (acc[m][n][j] - mean[m][j]) * rstd[m][j] * gg + bb;
      }
  }
}

// ---------------- MS-deform sampler v4: 16B gathers + XCD-chunked swizzle ----------------
__global__ __launch_bounds__(256)
void sampler_kernel(const float* __restrict__ offattn,   // [M][384]
                    const float* __restrict__ refp,      // [M][4][2]
                    const u16*  __restrict__ value,      // [M][256] bf16
                    u16*        __restrict__ src2)       // [M][256] bf16
{
  __shared__ float2 sWI[4][8][65];

  // bijective XCD-chunked swizzle: nwg=6647 = 7*831 + 830
  const int bid  = blockIdx.x;
  const int xcd  = bid & 7;
  const int idx  = bid >> 3;
  const int wg   = (xcd < 7) ? (xcd * 831 + idx) : (5817 + idx);

  const int t    = threadIdx.x;
  const int r4   = t >> 6;
  const int lane = t & 63;
  const int row  = wg * 4 + r4;
  const int b    = row / LQN;

  // ---- stage 1 ----
  {
    const float* oa = offattn + (size_t)row * 384;
    const float* rp = refp + (size_t)row * 8;
    const int p16 = lane & 15;
    const int l   = p16 >> 2;
    const int Wl  = (l == 0) ? 100 : (l == 1) ? 50 : (l == 2) ? 25 : 13;
    const int st  = (l == 0) ? 0 : (l == 1) ? 10000 : (l == 2) ? 12500 : 13125;
    const float rx = rp[l * 2 + 0] * (float)Wl - 0.5f;
    const float ry = rp[l * 2 + 1] * (float)Wl - 0.5f;

#pragma unroll
    for (int s = 0; s < 2; ++s) {
      const int h = s * 4 + (lane >> 4);
      float logit = oa[256 + h * 16 + p16];
      float mx = logit;
#pragma unroll
      for (int o = 1; o < 16; o <<= 1) mx = fmaxf(mx, __shfl_xor(mx, o, 64));
      float e = __expf(logit - mx);
      float ssum = e;
#pragma unroll
      for (int o = 1; o < 16; o <<= 1) ssum += __shfl_xor(ssum, o, 64);
      const float aw = e / ssum;

      const float ox = oa[(h * 16 + p16) * 2 + 0];
      const float oy = oa[(h * 16 + p16) * 2 + 1];
      const float gx = rx + ox;
      const float gy = ry + oy;
      const float x0f = floorf(gx), y0f = floorf(gy);
      const int   x0 = (int)x0f, y0 = (int)y0f;
      const float fx = gx - x0f, fy = gy - y0f;
#pragma unroll
      for (int c = 0; c < 4; ++c) {
        const int dx = c & 1, dy = c >> 1;
        const int xi = x0 + dx, yi = y0 + dy;
        const float wx = dx ? fx : 1.0f - fx;
        const float wy = dy ? fy : 1.0f - fy;
        const bool valid = (xi >= 0) && (xi < Wl) && (yi >= 0) && (yi < Wl);
        const int xc = min(max(xi, 0), Wl - 1);
        const int yc = min(max(yi, 0), Wl - 1);
        const int idxv = st + yc * Wl + xc;
        const float w = wx * wy * aw * (valid ? 1.0f : 0.0f);
        sWI[r4][h][p16 * 4 + c] = make_float2(w, __builtin_bit_cast(float, idxv));
      }
    }
  }
  __syncthreads();

  // ---- stage 2: 16B gathers, 2 entries per iter, shfl-combine ----
  {
    const int e2 = lane >> 5;
    const int h  = (lane >> 2) & 7;
    const int c8 = lane & 3;
    const char* vbase = (const char*)value + (size_t)b * LQN * 512 + h * 64 + c8 * 16;
    const float2* wi = sWI[r4][h];

    float a[8];
#pragma unroll
    for (int i = 0; i < 8; ++i) a[i] = 0.f;

#pragma unroll 8
    for (int e = 0; e < 64; e += 2) {
      const float2 p = wi[e + e2];
      const float w  = p.x;
      const int  idxv = __builtin_bit_cast(int, p.y);
      const u32x4 u = *(const u32x4*)(vbase + (size_t)idxv * 512);
#pragma unroll
      for (int i = 0; i < 4; ++i) {
        a[2 * i]     += w * bf2f((u16)(u[i]));
        a[2 * i + 1] += w * bf2f((u16)(u[i] >> 16));
      }
    }
#pragma unroll
    for (int i = 0; i < 8; ++i) a[i] += __shfl_xor(a[i], 32, 64);

    if (e2 == 0) {
      u16 o[8];
#pragma unroll
      for (int i = 0; i < 8; ++i) o[i] = f2bf(a[i]);
      *(short8*)&src2[(size_t)row * 256 + h * 32 + c8 * 8] = *(short8*)o;
    }
  }
}

// ---------------- merged prep: qsrc (bid<6647) + weights (bid>=6647) ----------------
__global__ __launch_bounds__(256)
void prep_all(const float* __restrict__ src, const float* __restrict__ pos,
              u16* __restrict__ src_bf, u16* __restrict__ q_bf,
              const float* __restrict__ w_value, const float* __restrict__ w_off,
              const float* __restrict__ w_attn,  const float* __restrict__ w_out,
              const float* __restrict__ w_ffn1,  const float* __restrict__ w_ffn2,
              const float* __restrict__ b_off,   const float* __restrict__ b_attn,
              u16* __restrict__ WT_val, u16* __restrict__ WT_oa, u16* __restrict__ WT_out,
              u16* __restrict__ WT_f1,  u16* __restrict__ WT_f2, float* __restrict__ bias_oa)
{
  if (blockIdx.x < 6647) {
    const size_t i = (size_t)blockIdx.x * 256 + threadIdx.x;
    const f32x4 s = ((const f32x4*)src)[i];
    const f32x4 p = ((const f32x4*)pos)[i];
    u16x4 sb, qb;
#pragma unroll
    for (int j = 0; j < 4; ++j) { sb[j] = f2bf(s[j]); qb[j] = f2bf(s[j] + p[j]); }
    ((u16x4*)src_bf)[i] = sb;
    ((u16x4*)q_bf)[i]   = qb;
    return;
  }
  int i = (blockIdx.x - 6647) * 256 + threadIdx.x;
  if (i < 65536) {
    const int k = i >> 8, n = i & 255;
    WT_val[n * 256 + k] = f2bf(w_value[i]);
  } else if ((i -= 65536) < 65536) {
    const int k = i >> 8, n = i & 255;
    WT_oa[n * 256 + k] = f2bf(w_off[i]);
  } else if ((i -= 65536) < 32768) {
    const int k = i >> 7, n = i & 127;
    WT_oa[(256 + n) * 256 + k] = f2bf(w_attn[i]);
  } else if ((i -= 32768) < 65536) {
    const int k = i >> 8, n = i & 255;
    WT_out[n * 256 + k] = f2bf(w_out[i]);
  } else if ((i -= 65536) < 524288) {
    const int k = i >> 11, n = i & 2047;
    WT_f1[n * 256 + k] = f2bf(w_ffn1[i]);
  } else if ((i -= 524288) < 524288) {
    const int k = i >> 8, n = i & 255;
    WT_f2[n * 2048 + k] = f2bf(w_ffn2[i]);
  } else if ((i -= 524288) < 384) {
    bias_oa[i] = (i < 256) ? b_off[i] : b_attn[i - 256];
  }
}

// ---------------- launch ----------------
extern "C" void kernel_launch(void* const* d_in, const int* in_sizes, int n_in,
                              void* d_out, int out_size, void* d_ws, size_t ws_size,
                              hipStream_t stream)
{
  const float* src     = (const float*)d_in[0];
  const float* pos     = (const float*)d_in[1];
  const float* refp    = (const float*)d_in[2];
  const float* w_value = (const float*)d_in[3];
  const float* b_value = (const float*)d_in[4];
  const float* w_off   = (const float*)d_in[5];
  const float* b_off   = (const float*)d_in[6];
  const float* w_attn  = (const float*)d_in[7];
  const float* b_attn  = (const float*)d_in[8];
  const float* w_out   = (const float*)d_in[9];
  const float* b_out   = (const float*)d_in[10];
  const float* ln1_g   = (const float*)d_in[11];
  const float* ln1_b   = (const float*)d_in[12];
  const float* w_ffn1  = (const float*)d_in[13];
  const float* b_ffn1  = (const float*)d_in[14];
  const float* w_ffn2  = (const float*)d_in[15];
  const float* b_ffn2  = (const float*)d_in[16];
  const float* ln2_g   = (const float*)d_in[17];
  const float* ln2_b   = (const float*)d_in[18];

  char* ws = (char*)d_ws;
  size_t off = 0;
  auto alloc = [&](size_t bytes) { void* p = ws + off; off += (bytes + 255) & ~(size_t)255; return p; };

  u16*   src_bf   = (u16*)  alloc((size_t)MROWS * 256 * 2);
  u16*   q_bf     = (u16*)  alloc((size_t)MROWS * 256 * 2);   // later: x_bf
  float* offattn  = (float*)alloc((size_t)MROWS * 384 * 4);
  u16*   value_bf = (u16*)  alloc((size_t)MROWS * 256 * 2);
  u16*   src2_bf  = (u16*)  alloc((size_t)MROWS * 256 * 2);
  float* x_f32    = (float*)alloc((size_t)MROWS * 256 * 4);
  u16*   WT_val   = (u16*)  alloc(256 * 256 * 2);
  u16*   WT_oa    = (u16*)  alloc(384 * 256 * 2);
  u16*   WT_out   = (u16*)  alloc(256 * 256 * 2);
  u16*   WT_f1    = (u16*)  alloc(2048 * 256 * 2);
  u16*   WT_f2    = (u16*)  alloc((size_t)256 * 2048 * 2);
  float* bias_oa  = (float*)alloc(384 * 4);

  u16* x_bf = q_bf;                  // alias (q_bf dead after gemm_dual)

  prep_all<<<6647 + 4994, 256, 0, stream>>>(src, pos, src_bf, q_bf,
                                            w_value, w_off, w_attn, w_out, w_ffn1, w_ffn2,
                                            b_off, b_attn,
                                            WT_val, WT_oa, WT_out, WT_f1, WT_f2, bias_oa);

  static bool attr_set = false;
  if (!attr_set) {
    hipFuncSetAttribute((const void*)ffn_ln2,
                        hipFuncAttributeMaxDynamicSharedMemorySize, 153600);
    hipFuncSetAttribute((const void*)outproj_ln1,
                        hipFuncAttributeMaxDynamicSharedMemorySize, 102400);
    attr_set = true;
  }

  // value-proj + off/attn-proj in one dispatch
  gemm_dual<<<dim3(208, 5), 256, 0, stream>>>(src_bf, WT_val, b_value, value_bf,
                                              q_bf, WT_oa, bias_oa, offattn);

  sampler_kernel<<<MROWS / 4, 256, 0, stream>>>(offattn, refp, value_bf, src2_bf);

  // out-proj + LN1 -> x_f32, x_bf
  outproj_ln1<<<208, 512, 102400, stream>>>(src2_bf, WT_out, b_out, src,
                                            ln1_g, ln1_b, x_f32, x_bf);

  // FFN + LN2 -> d_out
  ffn_ln2<<<208, 1024, 153600, stream>>>(x_bf, WT_f1, WT_f2, b_ffn1, b_ffn2,
                                         x_f32, ln2_g, ln2_b, (float*)d_out);
}

// Round 13
// 240.774 us; speedup vs baseline: 1.0641x; 1.0641x over previous
//
#include <hip/hip_runtime.h>

// ---------------- static problem config ----------------
#define LQN   13294
#define NBAT  2
#define MROWS (NBAT * LQN)   // 26588
#define CCH   256
#define NHEAD 8
#define DHEAD 32
#define NLVL  4
#define NPT   4
#define DFF   2048

typedef short short8 __attribute__((ext_vector_type(8)));
typedef float f32x4 __attribute__((ext_vector_type(4)));
typedef unsigned short u16;
typedef u16 u16x4 __attribute__((ext_vector_type(4)));
typedef unsigned int u32;
typedef u32 u32x4 __attribute__((ext_vector_type(4)));

__device__ __forceinline__ u16 f2bf(float f) {
  unsigned int u = __builtin_bit_cast(unsigned int, f);
  u += 0x7fffu + ((u >> 16) & 1u);   // RNE
  return (u16)(u >> 16);
}
__device__ __forceinline__ float bf2f(u16 s) {
  unsigned int u = ((unsigned int)s) << 16;
  return __builtin_bit_cast(float, u);
}
__device__ __forceinline__ void async16(const void* g, void* l) {
  __builtin_amdgcn_global_load_lds(
      (const __attribute__((address_space(1))) void*)g,
      (__attribute__((address_space(3))) void*)l, 16, 0, 0);
}

// ---------------- dual GEMM: value-proj (bn<2, bf16 out) + off/attn-proj (bn>=2, f32) ----------------
__global__ __launch_bounds__(256, 2)
void gemm_dual(const u16* __restrict__ A0, const u16* __restrict__ BT0,
               const float* __restrict__ bias0, u16* __restrict__ C0,
               const u16* __restrict__ A1, const u16* __restrict__ BT1,
               const float* __restrict__ bias1, float* __restrict__ C1)
{
  __shared__ u16 As[2][128 * 64];
  __shared__ u16 Bs[2][128 * 64];
  const int t    = threadIdx.x;
  const int lane = t & 63;
  const int wid  = t >> 6;
  const int wm   = wid >> 1, wn = wid & 1;
  const int bm   = blockIdx.x;
  const int bnG  = blockIdx.y;
  const bool first = bnG < 2;
  const u16* A    = first ? A0 : A1;
  const u16* BT   = first ? BT0 : BT1;
  const float* bias = first ? bias0 : bias1;
  const int  bn   = first ? bnG : bnG - 2;
  const int l15  = lane & 15;
  const int kq   = lane >> 4;

  f32x4 acc[4][4];
#pragma unroll
  for (int m = 0; m < 4; ++m)
#pragma unroll
    for (int n = 0; n < 4; ++n) acc[m][n] = (f32x4)0.0f;

  auto stage = [&](int buf, int kt) {
#pragma unroll
    for (int i = 0; i < 4; ++i) {
      const int c   = i * 256 + t;
      const int row = c >> 3;
      const int kg  = (c & 7) ^ (row & 7);
      int ar = bm * 128 + row; ar = ar < MROWS ? ar : MROWS - 1;
      async16(&A[(size_t)ar * 256 + kt + kg * 8], &As[buf][c * 8]);
      const int br = bn * 128 + row;
      async16(&BT[(size_t)br * 256 + kt + kg * 8], &Bs[buf][c * 8]);
    }
  };

  stage(0, 0);
  __syncthreads();
  int cur = 0;

  for (int kt = 0; kt < 256; kt += 64) {
    if (kt + 64 < 256) stage(cur ^ 1, kt + 64);

#pragma unroll
    for (int kk = 0; kk < 2; ++kk) {
      short8 af[4], bfr[4];
#pragma unroll
      for (int m = 0; m < 4; ++m) {
        const int row = wm * 64 + m * 16 + l15;
        const int xb  = (kk * 64 + kq * 16) ^ ((row & 7) << 4);
        af[m] = *(const short8*)((const char*)&As[cur][0] + row * 128 + xb);
      }
#pragma unroll
      for (int n = 0; n < 4; ++n) {
        const int col = wn * 64 + n * 16 + l15;
        const int xb  = (kk * 64 + kq * 16) ^ ((col & 7) << 4);
        bfr[n] = *(const short8*)((const char*)&Bs[cur][0] + col * 128 + xb);
      }
#pragma unroll
      for (int m = 0; m < 4; ++m)
#pragma unroll
        for (int n = 0; n < 4; ++n)
          acc[m][n] = __builtin_amdgcn_mfma_f32_16x16x32_bf16(af[m], bfr[n], acc[m][n], 0, 0, 0);
    }

    __syncthreads();
    cur ^= 1;
  }

  const int crow0 = bm * 128 + wm * 64;
  const int ccol0 = bn * 128 + wn * 64;
#pragma unroll
  for (int n = 0; n < 4; ++n) {
    int col = ccol0 + n * 16 + l15;
    float bv = bias[col];
#pragma unroll
    for (int m = 0; m < 4; ++m) {
      int rbase = crow0 + m * 16 + kq * 4;
#pragma unroll
      for (int j = 0; j < 4; ++j) {
        int row = rbase + j;
        if (row < MROWS) {
          float v = acc[m][n][j] + bv;
          if (first) C0[(size_t)row * 256 + col] = f2bf(v);
          else       C1[(size_t)row * 384 + col] = v;
        }
      }
    }
  }
}

// ---------------- out-proj + LN1 fused (single-buffered, 2 blocks/CU) ----------------
__global__ __launch_bounds__(512, 2)
void outproj_ln1(const u16* __restrict__ src2_bf, const u16* __restrict__ WT_out,
                 const float* __restrict__ b_out, const float* __restrict__ src,
                 const float* __restrict__ g1, const float* __restrict__ be1,
                 float* __restrict__ x_f32, u16* __restrict__ x_bf)
{
  extern __shared__ char smem[];
  char* As = smem;                  // [128][128B] 16KB
  char* Bs = smem + 16384;          // [256][128B] 32KB
  float2* red = (float2*)(smem + 49152);   // [128][4] 4KB

  const int t    = threadIdx.x;
  const int lane = t & 63;
  const int wid  = t >> 6;
  const int wm   = wid >> 2, wn = wid & 3;   // 2x4 waves, tile 64x64
  const int l15  = lane & 15;
  const int kq   = lane >> 4;
  const int bm   = blockIdx.x;

  auto stage = [&](int kt) {
#pragma unroll
    for (int i = 0; i < 2; ++i) {
      const int c   = i * 512 + t;
      const int row = c >> 3;
      const int kg  = (c & 7) ^ (row & 7);
      int ar = bm * 128 + row; ar = ar < MROWS ? ar : MROWS - 1;
      async16(&src2_bf[(size_t)ar * 256 + kt + kg * 8], As + c * 16);
    }
#pragma unroll
    for (int i = 0; i < 4; ++i) {
      const int c   = i * 512 + t;
      const int row = c >> 3;
      const int kg  = (c & 7) ^ (row & 7);
      async16(&WT_out[(size_t)row * 256 + kt + kg * 8], Bs + c * 16);
    }
  };

  f32x4 acc[4][4];
#pragma unroll
  for (int m = 0; m < 4; ++m)
#pragma unroll
    for (int n = 0; n < 4; ++n) acc[m][n] = (f32x4)0.0f;

  for (int kt = 0; kt < 256; kt += 64) {
    stage(kt);
    __syncthreads();

#pragma unroll
    for (int kk = 0; kk < 2; ++kk) {
      short8 af[4], bfr[4];
#pragma unroll
      for (int m = 0; m < 4; ++m) {
        const int row = wm * 64 + m * 16 + l15;
        const int xb  = (kk * 64 + kq * 16) ^ ((row & 7) << 4);
        af[m] = *(const short8*)(As + row * 128 + xb);
      }
#pragma unroll
      for (int n = 0; n < 4; ++n) {
        const int col = wn * 64 + n * 16 + l15;
        const int xb  = (kk * 64 + kq * 16) ^ ((col & 7) << 4);
        bfr[n] = *(const short8*)(Bs + col * 128 + xb);
      }
#pragma unroll
      for (int m = 0; m < 4; ++m)
#pragma unroll
        for (int n = 0; n < 4; ++n)
          acc[m][n] = __builtin_amdgcn_mfma_f32_16x16x32_bf16(af[m], bfr[n], acc[m][n], 0, 0, 0);
    }
    __syncthreads();
  }

  // ---- epilogue: v = acc + b_out + src ; LN1 ; write x_f32, x_bf ----
#pragma unroll
  for (int n = 0; n < 4; ++n) {
    const int col = wn * 64 + n * 16 + l15;
    const float bv = b_out[col];
#pragma unroll
    for (int m = 0; m < 4; ++m)
#pragma unroll
      for (int j = 0; j < 4; ++j) {
        int row = bm * 128 + wm * 64 + m * 16 + kq * 4 + j;
        row = row < MROWS ? row : MROWS - 1;
        acc[m][n][j] += bv + src[(size_t)row * 256 + col];
      }
  }
  float s1[4][4], s2[4][4];
#pragma unroll
  for (int m = 0; m < 4; ++m)
#pragma unroll
    for (int j = 0; j < 4; ++j) {
      float a = 0.f, b = 0.f;
#pragma unroll
      for (int n = 0; n < 4; ++n) { const float v = acc[m][n][j]; a += v; b += v * v; }
      s1[m][j] = a; s2[m][j] = b;
    }
#pragma unroll
  for (int o = 1; o < 16; o <<= 1)
#pragma unroll
    for (int m = 0; m < 4; ++m)
#pragma unroll
      for (int j = 0; j < 4; ++j) {
        s1[m][j] += __shfl_xor(s1[m][j], o, 64);
        s2[m][j] += __shfl_xor(s2[m][j], o, 64);
      }
  if (l15 == 0)
#pragma unroll
    for (int m = 0; m < 4; ++m)
#pragma unroll
      for (int j = 0; j < 4; ++j)
        red[(wm * 64 + m * 16 + kq * 4 + j) * 4 + wn] = make_float2(s1[m][j], s2[m][j]);
  __syncthreads();
  float mean[4][4], rstd[4][4];
#pragma unroll
  for (int m = 0; m < 4; ++m)
#pragma unroll
    for (int j = 0; j < 4; ++j) {
      const int rl = wm * 64 + m * 16 + kq * 4 + j;
      float a = 0.f, b = 0.f;
#pragma unroll
      for (int w = 0; w < 4; ++w) { const float2 r = red[rl * 4 + w]; a += r.x; b += r.y; }
      const float mu = a * (1.0f / 256.0f);
      mean[m][j] = mu;
      rstd[m][j] = rsqrtf(b * (1.0f / 256.0f) - mu * mu + 1e-5f);
    }
#pragma unroll
  for (int n = 0; n < 4; ++n) {
    const int col = wn * 64 + n * 16 + l15;
    const float gg = g1[col], bb = be1[col];
#pragma unroll
    for (int m = 0; m < 4; ++m)
#pragma unroll
      for (int j = 0; j < 4; ++j) {
        const int row = bm * 128 + wm * 64 + m * 16 + kq * 4 + j;
        if (row < MROWS) {
          const float y = (acc[m][n][j] - mean[m][j]) * rstd[m][j] * gg + bb;
          x_f32[(size_t)row * 256 + col] = y;
          x_bf[(size_t)row * 256 + col] = f2bf(y);
        }
      }
  }
}

// ---------------- fused FFN + LN2 (r9 v4 EXACT, measured 102us) ----------------
__global__ __launch_bounds__(1024, 2)
void ffn_ln2(const u16* __restrict__ x_bf, const u16* __restrict__ W1T,
             const u16* __restrict__ W2T, const float* __restrict__ b1,
             const float* __restrict__ b2, const float* __restrict__ x_f32,
             const float* __restrict__ g2, const float* __restrict__ be2,
             float* __restrict__ out)
{
  extern __shared__ char smem[];
  u16*  w1s = (u16*)(smem);            // [2][64][256]
  u16*  w2s = (u16*)(smem + 65536);    // [2][256][64]
  char* ps  = smem + 131072;           // [128][144B]
  float2* red = (float2*)(smem + 149504);  // [128][4]

  const int t    = threadIdx.x;
  const int lane = t & 63;
  const int wid  = t >> 6;             // 0..15
  const int l15  = lane & 15;
  const int kq   = lane >> 4;
  const int bm   = blockIdx.x;
  const int pwm  = wid >> 1, pwn = wid & 1;   // P: 8x2, tile 16x32
  const int vwm  = wid >> 2, vwn = wid & 3;   // PV: 4x4, tile 32x64

  short8 xr[8];
  {
    int ar = bm * 128 + pwm * 16 + l15;
    ar = ar < MROWS ? ar : MROWS - 1;
    const char* xb = (const char*)x_bf + (size_t)ar * 512 + kq * 16;
#pragma unroll
    for (int ks = 0; ks < 8; ++ks) xr[ks] = *(const short8*)(xb + ks * 64);
  }

  auto stage = [&](int buf, int it) {
#pragma unroll
    for (int i = 0; i < 2; ++i) {
      const int c  = i * 1024 + t;
      const int r1 = c >> 5;
      const int k1 = ((c & 31) ^ (r1 & 7)) * 8;
      async16(&W1T[(size_t)(it * 64 + r1) * 256 + k1], &w1s[buf * 16384 + c * 8]);
      const int r2 = c >> 3;
      const int k2 = ((c & 7) ^ (r2 & 7)) * 8;
      async16(&W2T[(size_t)r2 * 2048 + it * 64 + k2], &w2s[buf * 16384 + c * 8]);
    }
  };

  f32x4 acc[2][4];
#pragma unroll
  for (int m = 0; m < 2; ++m)
#pragma unroll
    for (int n = 0; n < 4; ++n) acc[m][n] = (f32x4)0.0f;

  stage(0, 0);
  __syncthreads();

  for (int it = 0; it < 32; ++it) {
    const int cur = it & 1;
    if (it < 31) stage(cur ^ 1, it + 1);

    f32x4 p[2];
    p[0] = (f32x4)0.0f; p[1] = (f32x4)0.0f;
#pragma unroll
    for (int ks = 0; ks < 8; ++ks) {
#pragma unroll
      for (int n = 0; n < 2; ++n) {
        const int wrow = pwn * 32 + n * 16 + l15;
        const int xb   = (((ks * 4 + kq) ^ (wrow & 7)) << 4);
        const short8 bfr = *(const short8*)((const char*)&w1s[cur * 16384] + wrow * 512 + xb);
        p[n] = __builtin_amdgcn_mfma_f32_16x16x32_bf16(xr[ks], bfr, p[n], 0, 0, 0);
      }
    }

#pragma unroll
    for (int n = 0; n < 2; ++n) {
      const int col = pwn * 32 + n * 16 + l15;
      const float bv = b1[it * 64 + col];
#pragma unroll
      for (int j = 0; j < 4; ++j) {
        const int prow = pwm * 16 + kq * 4 + j;
        *(u16*)(ps + prow * 144 + col * 2) = f2bf(fmaxf(p[n][j] + bv, 0.0f));
      }
    }
    __syncthreads();

#pragma unroll
    for (int kk = 0; kk < 2; ++kk) {
      short8 paf[2];
#pragma unroll
      for (int m = 0; m < 2; ++m) {
        const int arow = vwm * 32 + m * 16 + l15;
        paf[m] = *(const short8*)(ps + arow * 144 + (kk * 4 + kq) * 16);
      }
#pragma unroll
      for (int n = 0; n < 4; ++n) {
        const int brow = vwn * 64 + n * 16 + l15;
        const int xb   = (((kk * 4 + kq) ^ (brow & 7)) << 4);
        const short8 bfr = *(const short8*)((const char*)&w2s[cur * 16384] + brow * 128 + xb);
#pragma unroll
        for (int m = 0; m < 2; ++m)
          acc[m][n] = __builtin_amdgcn_mfma_f32_16x16x32_bf16(paf[m], bfr, acc[m][n], 0, 0, 0);
      }
    }
    __syncthreads();
  }

  // ---- epilogue: v = acc + b2 + x ; LN2 ; write d_out ----
#pragma unroll
  for (int n = 0; n < 4; ++n) {
    const int col = vwn * 64 + n * 16 + l15;
    const float bv = b2[col];
#pragma unroll
    for (int m = 0; m < 2; ++m)
#pragma unroll
      for (int j = 0; j < 4; ++j) {
        int row = bm * 128 + vwm * 32 + m * 16 + kq * 4 + j;
        row = row < MROWS ? row : MROWS - 1;
        acc[m][n][j] += bv + x_f32[(size_t)row * 256 + col];
      }
  }
  float s1[2][4], s2[2][4];
#pragma unroll
  for (int m = 0; m < 2; ++m)
#pragma unroll
    for (int j = 0; j < 4; ++j) {
      float a = 0.f, b = 0.f;
#pragma unroll
      for (int n = 0; n < 4; ++n) { const float v = acc[m][n][j]; a += v; b += v * v; }
      s1[m][j] = a; s2[m][j] = b;
    }
#pragma unroll
  for (int o = 1; o < 16; o <<= 1)
#pragma unroll
    for (int m = 0; m < 2; ++m)
#pragma unroll
      for (int j = 0; j < 4; ++j) {
        s1[m][j] += __shfl_xor(s1[m][j], o, 64);
        s2[m][j] += __shfl_xor(s2[m][j], o, 64);
      }
  if (l15 == 0)
#pragma unroll
    for (int m = 0; m < 2; ++m)
#pragma unroll
      for (int j = 0; j < 4; ++j)
        red[(vwm * 32 + m * 16 + kq * 4 + j) * 4 + vwn] = make_float2(s1[m][j], s2[m][j]);
  __syncthreads();
  float mean[2][4], rstd[2][4];
#pragma unroll
  for (int m = 0; m < 2; ++m)
#pragma unroll
    for (int j = 0; j < 4; ++j) {
      const int rl = vwm * 32 + m * 16 + kq * 4 + j;
      float a = 0.f, b = 0.f;
#pragma unroll
      for (int w = 0; w < 4; ++w) { const float2 r = red[rl * 4 + w]; a += r.x; b += r.y; }
      const float mu = a * (1.0f / 256.0f);
      mean[m][j] = mu;
      rstd[m][j] = rsqrtf(b * (1.0f / 256.0f) - mu * mu + 1e-5f);
    }
#pragma unroll
  for (int n = 0; n < 4; ++n) {
    const int col = vwn * 64 + n * 16 + l15;
    const float gg = g2[col], bb = be2[col];
#pragma unroll
    for (int m = 0; m < 2; ++m)
#pragma unroll
      for (int j = 0; j < 4; ++j) {
        const int row = bm * 128 + vwm * 32 + m * 16 + kq * 4 + j;
        if (row < MROWS)
          out[(size_t)row * 256 + col] = (acc[m][n][j] - mean[m][j]) * rstd[m][j] * gg + bb;
      }
  }
}

// ---------------- MS-deform sampler v4 (r11 state) ----------------
__global__ __launch_bounds__(256)
void sampler_kernel(const float* __restrict__ offattn,   // [M][384]
                    const float* __restrict__ refp,      // [M][4][2]
                    const u16*  __restrict__ value,      // [M][256] bf16
                    u16*        __restrict__ src2)       // [M][256] bf16
{
  __shared__ float2 sWI[4][8][65];

  // bijective XCD-chunked swizzle: nwg=6647 = 7*831 + 830
  const int bid  = blockIdx.x;
  const int xcd  = bid & 7;
  const int idx  = bid >> 3;
  const int wg   = (xcd < 7) ? (xcd * 831 + idx) : (5817 + idx);

  const int t    = threadIdx.x;
  const int r4   = t >> 6;
  const int lane = t & 63;
  const int row  = wg * 4 + r4;
  const int b    = row / LQN;

  {
    const float* oa = offattn + (size_t)row * 384;
    const float* rp = refp + (size_t)row * 8;
    const int p16 = lane & 15;
    const int l   = p16 >> 2;
    const int Wl  = (l == 0) ? 100 : (l == 1) ? 50 : (l == 2) ? 25 : 13;
    const int st  = (l == 0) ? 0 : (l == 1) ? 10000 : (l == 2) ? 12500 : 13125;
    const float rx = rp[l * 2 + 0] * (float)Wl - 0.5f;
    const float ry = rp[l * 2 + 1] * (float)Wl - 0.5f;

#pragma unroll
    for (int s = 0; s < 2; ++s) {
      const int h = s * 4 + (lane >> 4);
      float logit = oa[256 + h * 16 + p16];
      float mx = logit;
#pragma unroll
      for (int o = 1; o < 16; o <<= 1) mx = fmaxf(mx, __shfl_xor(mx, o, 64));
      float e = __expf(logit - mx);
      float ssum = e;
#pragma unroll
      for (int o = 1; o < 16; o <<= 1) ssum += __shfl_xor(ssum, o, 64);
      const float aw = e / ssum;

      const float ox = oa[(h * 16 + p16) * 2 + 0];
      const float oy = oa[(h * 16 + p16) * 2 + 1];
      const float gx = rx + ox;
      const float gy = ry + oy;
      const float x0f = floorf(gx), y0f = floorf(gy);
      const int   x0 = (int)x0f, y0 = (int)y0f;
      const float fx = gx - x0f, fy = gy - y0f;
#pragma unroll
      for (int c = 0; c < 4; ++c) {
        const int dx = c & 1, dy = c >> 1;
        const int xi = x0 + dx, yi = y0 + dy;
        const float wx = dx ? fx : 1.0f - fx;
        const float wy = dy ? fy : 1.0f - fy;
        const bool valid = (xi >= 0) && (xi < Wl) && (yi >= 0) && (yi < Wl);
        const int xc = min(max(xi, 0), Wl - 1);
        const int yc = min(max(yi, 0), Wl - 1);
        const int idxv = st + yc * Wl + xc;
        const float w = wx * wy * aw * (valid ? 1.0f : 0.0f);
        sWI[r4][h][p16 * 4 + c] = make_float2(w, __builtin_bit_cast(float, idxv));
      }
    }
  }
  __syncthreads();

  {
    const int e2 = lane >> 5;
    const int h  = (lane >> 2) & 7;
    const int c8 = lane & 3;
    const char* vbase = (const char*)value + (size_t)b * LQN * 512 + h * 64 + c8 * 16;
    const float2* wi = sWI[r4][h];

    float a[8];
#pragma unroll
    for (int i = 0; i < 8; ++i) a[i] = 0.f;

#pragma unroll 8
    for (int e = 0; e < 64; e += 2) {
      const float2 p = wi[e + e2];
      const float w  = p.x;
      const int  idxv = __builtin_bit_cast(int, p.y);
      const u32x4 u = *(const u32x4*)(vbase + (size_t)idxv * 512);
#pragma unroll
      for (int i = 0; i < 4; ++i) {
        a[2 * i]     += w * bf2f((u16)(u[i]));
        a[2 * i + 1] += w * bf2f((u16)(u[i] >> 16));
      }
    }
#pragma unroll
    for (int i = 0; i < 8; ++i) a[i] += __shfl_xor(a[i], 32, 64);

    if (e2 == 0) {
      u16 o[8];
#pragma unroll
      for (int i = 0; i < 8; ++i) o[i] = f2bf(a[i]);
      *(short8*)&src2[(size_t)row * 256 + h * 32 + c8 * 8] = *(short8*)o;
    }
  }
}

// ---------------- merged prep: qsrc (bid<6647) + weights (bid>=6647) ----------------
__global__ __launch_bounds__(256)
void prep_all(const float* __restrict__ src, const float* __restrict__ pos,
              u16* __restrict__ src_bf, u16* __restrict__ q_bf,
              const float* __restrict__ w_value, const float* __restrict__ w_off,
              const float* __restrict__ w_attn,  const float* __restrict__ w_out,
              const float* __restrict__ w_ffn1,  const float* __restrict__ w_ffn2,
              const float* __restrict__ b_off,   const float* __restrict__ b_attn,
              u16* __restrict__ WT_val, u16* __restrict__ WT_oa, u16* __restrict__ WT_out,
              u16* __restrict__ WT_f1,  u16* __restrict__ WT_f2, float* __restrict__ bias_oa)
{
  if (blockIdx.x < 6647) {
    const size_t i = (size_t)blockIdx.x * 256 + threadIdx.x;
    const f32x4 s = ((const f32x4*)src)[i];
    const f32x4 p = ((const f32x4*)pos)[i];
    u16x4 sb, qb;
#pragma unroll
    for (int j = 0; j < 4; ++j) { sb[j] = f2bf(s[j]); qb[j] = f2bf(s[j] + p[j]); }
    ((u16x4*)src_bf)[i] = sb;
    ((u16x4*)q_bf)[i]   = qb;
    return;
  }
  int i = (blockIdx.x - 6647) * 256 + threadIdx.x;
  if (i < 65536) {
    const int k = i >> 8, n = i & 255;
    WT_val[n * 256 + k] = f2bf(w_value[i]);
  } else if ((i -= 65536) < 65536) {
    const int k = i >> 8, n = i & 255;
    WT_oa[n * 256 + k] = f2bf(w_off[i]);
  } else if ((i -= 65536) < 32768) {
    const int k = i >> 7, n = i & 127;
    WT_oa[(256 + n) * 256 + k] = f2bf(w_attn[i]);
  } else if ((i -= 32768) < 65536) {
    const int k = i >> 8, n = i & 255;
    WT_out[n * 256 + k] = f2bf(w_out[i]);
  } else if ((i -= 65536) < 524288) {
    const int k = i >> 11, n = i & 2047;
    WT_f1[n * 256 + k] = f2bf(w_ffn1[i]);
  } else if ((i -= 524288) < 524288) {
    const int k = i >> 8, n = i & 255;
    WT_f2[n * 2048 + k] = f2bf(w_ffn2[i]);
  } else if ((i -= 524288) < 384) {
    bias_oa[i] = (i < 256) ? b_off[i] : b_attn[i - 256];
  }
}

// ---------------- launch ----------------
extern "C" void kernel_launch(void* const* d_in, const int* in_sizes, int n_in,
                              void* d_out, int out_size, void* d_ws, size_t ws_size,
                              hipStream_t stream)
{
  const float* src     = (const float*)d_in[0];
  const float* pos     = (const float*)d_in[1];
  const float* refp    = (const float*)d_in[2];
  const float* w_value = (const float*)d_in[3];
  const float* b_value = (const float*)d_in[4];
  const float* w_off   = (const float*)d_in[5];
  const float* b_off   = (const float*)d_in[6];
  const float* w_attn  = (const float*)d_in[7];
  const float* b_attn  = (const float*)d_in[8];
  const float* w_out   = (const float*)d_in[9];
  const float* b_out   = (const float*)d_in[10];
  const float* ln1_g   = (const float*)d_in[11];
  const float* ln1_b   = (const float*)d_in[12];
  const float* w_ffn1  = (const float*)d_in[13];
  const float* b_ffn1  = (const float*)d_in[14];
  const float* w_ffn2  = (const float*)d_in[15];
  const float* b_ffn2  = (const float*)d_in[16];
  const float* ln2_g   = (const float*)d_in[17];
  const float* ln2_b   = (const float*)d_in[18];

  char* ws = (char*)d_ws;
  size_t off = 0;
  auto alloc = [&](size_t bytes) { void* p = ws + off; off += (bytes + 255) & ~(size_t)255; return p; };

  u16*   src_bf   = (u16*)  alloc((size_t)MROWS * 256 * 2);
  u16*   q_bf     = (u16*)  alloc((size_t)MROWS * 256 * 2);   // later: x_bf
  float* offattn  = (float*)alloc((size_t)MROWS * 384 * 4);
  u16*   value_bf = (u16*)  alloc((size_t)MROWS * 256 * 2);
  u16*   src2_bf  = (u16*)  alloc((size_t)MROWS * 256 * 2);
  float* x_f32    = (float*)alloc((size_t)MROWS * 256 * 4);
  u16*   WT_val   = (u16*)  alloc(256 * 256 * 2);
  u16*   WT_oa    = (u16*)  alloc(384 * 256 * 2);
  u16*   WT_out   = (u16*)  alloc(256 * 256 * 2);
  u16*   WT_f1    = (u16*)  alloc(2048 * 256 * 2);
  u16*   WT_f2    = (u16*)  alloc((size_t)256 * 2048 * 2);
  float* bias_oa  = (float*)alloc(384 * 4);

  u16* x_bf = q_bf;                  // alias (q_bf dead after gemm_dual)

  prep_all<<<6647 + 4994, 256, 0, stream>>>(src, pos, src_bf, q_bf,
                                            w_value, w_off, w_attn, w_out, w_ffn1, w_ffn2,
                                            b_off, b_attn,
                                            WT_val, WT_oa, WT_out, WT_f1, WT_f2, bias_oa);

  static bool attr_set = false;
  if (!attr_set) {
    hipFuncSetAttribute((const void*)ffn_ln2,
                        hipFuncAttributeMaxDynamicSharedMemorySize, 153600);
    hipFuncSetAttribute((const void*)outproj_ln1,
                        hipFuncAttributeMaxDynamicSharedMemorySize, 53248);
    attr_set = true;
  }

  // value-proj + off/attn-proj in one dispatch
  gemm_dual<<<dim3(208, 5), 256, 0, stream>>>(src_bf, WT_val, b_value, value_bf,
                                              q_bf, WT_oa, bias_oa, offattn);

  sampler_kernel<<<MROWS / 4, 256, 0, stream>>>(offattn, refp, value_bf, src2_bf);

  // out-proj + LN1 -> x_f32, x_bf
  outproj_ln1<<<208, 512, 53248, stream>>>(src2_bf, WT_out, b_out, src,
                                           ln1_g, ln1_b, x_f32, x_bf);

  // FFN + LN2 -> d_out
  ffn_ln2<<<208, 1024, 153600, stream>>>(x_bf, WT_f1, WT_f2, b_ffn1, b_ffn2,
                                         x_f32, ln2_g, ln2_b, (float*)d_out);
}

// Round 14
// 236.293 us; speedup vs baseline: 1.0842x; 1.0190x over previous
//
#include <hip/hip_runtime.h>

// ---------------- static problem config ----------------
#define LQN   13294
#define NBAT  2
#define MROWS (NBAT * LQN)   // 26588
#define CCH   256
#define NHEAD 8
#define DHEAD 32
#define NLVL  4
#define NPT   4
#define DFF   2048

typedef short short8 __attribute__((ext_vector_type(8)));
typedef float f32x4 __attribute__((ext_vector_type(4)));
typedef unsigned short u16;
typedef u16 u16x4 __attribute__((ext_vector_type(4)));
typedef unsigned int u32;
typedef u32 u32x4 __attribute__((ext_vector_type(4)));

__device__ __forceinline__ u16 f2bf(float f) {
  unsigned int u = __builtin_bit_cast(unsigned int, f);
  u += 0x7fffu + ((u >> 16) & 1u);   // RNE
  return (u16)(u >> 16);
}
__device__ __forceinline__ float bf2f(u16 s) {
  unsigned int u = ((unsigned int)s) << 16;
  return __builtin_bit_cast(float, u);
}
__device__ __forceinline__ void async16(const void* g, void* l) {
  __builtin_amdgcn_global_load_lds(
      (const __attribute__((address_space(1))) void*)g,
      (__attribute__((address_space(3))) void*)l, 16, 0, 0);
}

// ---------------- dual GEMM: value-proj (bn<2) + off/attn-proj (bn>=2), both bf16 out ----------------
__global__ __launch_bounds__(256, 2)
void gemm_dual(const u16* __restrict__ A0, const u16* __restrict__ BT0,
               const float* __restrict__ bias0, u16* __restrict__ C0,
               const u16* __restrict__ A1, const u16* __restrict__ BT1,
               const float* __restrict__ bias1, u16* __restrict__ C1)
{
  __shared__ u16 As[2][128 * 64];
  __shared__ u16 Bs[2][128 * 64];
  const int t    = threadIdx.x;
  const int lane = t & 63;
  const int wid  = t >> 6;
  const int wm   = wid >> 1, wn = wid & 1;
  const int bm   = blockIdx.x;
  const int bnG  = blockIdx.y;
  const bool first = bnG < 2;
  const u16* A    = first ? A0 : A1;
  const u16* BT   = first ? BT0 : BT1;
  const float* bias = first ? bias0 : bias1;
  const int  bn   = first ? bnG : bnG - 2;
  const int l15  = lane & 15;
  const int kq   = lane >> 4;

  f32x4 acc[4][4];
#pragma unroll
  for (int m = 0; m < 4; ++m)
#pragma unroll
    for (int n = 0; n < 4; ++n) acc[m][n] = (f32x4)0.0f;

  auto stage = [&](int buf, int kt) {
#pragma unroll
    for (int i = 0; i < 4; ++i) {
      const int c   = i * 256 + t;
      const int row = c >> 3;
      const int kg  = (c & 7) ^ (row & 7);
      int ar = bm * 128 + row; ar = ar < MROWS ? ar : MROWS - 1;
      async16(&A[(size_t)ar * 256 + kt + kg * 8], &As[buf][c * 8]);
      const int br = bn * 128 + row;
      async16(&BT[(size_t)br * 256 + kt + kg * 8], &Bs[buf][c * 8]);
    }
  };

  stage(0, 0);
  __syncthreads();
  int cur = 0;

  for (int kt = 0; kt < 256; kt += 64) {
    if (kt + 64 < 256) stage(cur ^ 1, kt + 64);

#pragma unroll
    for (int kk = 0; kk < 2; ++kk) {
      short8 af[4], bfr[4];
#pragma unroll
      for (int m = 0; m < 4; ++m) {
        const int row = wm * 64 + m * 16 + l15;
        const int xb  = (kk * 64 + kq * 16) ^ ((row & 7) << 4);
        af[m] = *(const short8*)((const char*)&As[cur][0] + row * 128 + xb);
      }
#pragma unroll
      for (int n = 0; n < 4; ++n) {
        const int col = wn * 64 + n * 16 + l15;
        const int xb  = (kk * 64 + kq * 16) ^ ((col & 7) << 4);
        bfr[n] = *(const short8*)((const char*)&Bs[cur][0] + col * 128 + xb);
      }
#pragma unroll
      for (int m = 0; m < 4; ++m)
#pragma unroll
        for (int n = 0; n < 4; ++n)
          acc[m][n] = __builtin_amdgcn_mfma_f32_16x16x32_bf16(af[m], bfr[n], acc[m][n], 0, 0, 0);
    }

    __syncthreads();
    cur ^= 1;
  }

  const int crow0 = bm * 128 + wm * 64;
  const int ccol0 = bn * 128 + wn * 64;
#pragma unroll
  for (int n = 0; n < 4; ++n) {
    int col = ccol0 + n * 16 + l15;
    float bv = bias[col];
#pragma unroll
    for (int m = 0; m < 4; ++m) {
      int rbase = crow0 + m * 16 + kq * 4;
#pragma unroll
      for (int j = 0; j < 4; ++j) {
        int row = rbase + j;
        if (row < MROWS) {
          float v = acc[m][n][j] + bv;
          if (first) C0[(size_t)row * 256 + col] = f2bf(v);
          else       C1[(size_t)row * 384 + col] = f2bf(v);
        }
      }
    }
  }
}

// ---------------- out-proj + LN1 fused (single-buffered; writes x_bf only) ----------------
__global__ __launch_bounds__(512, 2)
void outproj_ln1(const u16* __restrict__ src2_bf, const u16* __restrict__ WT_out,
                 const float* __restrict__ b_out, const float* __restrict__ src,
                 const float* __restrict__ g1, const float* __restrict__ be1,
                 u16* __restrict__ x_bf)
{
  extern __shared__ char smem[];
  char* As = smem;                  // [128][128B] 16KB
  char* Bs = smem + 16384;          // [256][128B] 32KB
  float2* red = (float2*)(smem + 49152);   // [128][4] 4KB

  const int t    = threadIdx.x;
  const int lane = t & 63;
  const int wid  = t >> 6;
  const int wm   = wid >> 2, wn = wid & 3;   // 2x4 waves, tile 64x64
  const int l15  = lane & 15;
  const int kq   = lane >> 4;
  const int bm   = blockIdx.x;

  auto stage = [&](int kt) {
#pragma unroll
    for (int i = 0; i < 2; ++i) {
      const int c   = i * 512 + t;
      const int row = c >> 3;
      const int kg  = (c & 7) ^ (row & 7);
      int ar = bm * 128 + row; ar = ar < MROWS ? ar : MROWS - 1;
      async16(&src2_bf[(size_t)ar * 256 + kt + kg * 8], As + c * 16);
    }
#pragma unroll
    for (int i = 0; i < 4; ++i) {
      const int c   = i * 512 + t;
      const int row = c >> 3;
      const int kg  = (c & 7) ^ (row & 7);
      async16(&WT_out[(size_t)row * 256 + kt + kg * 8], Bs + c * 16);
    }
  };

  f32x4 acc[4][4];
#pragma unroll
  for (int m = 0; m < 4; ++m)
#pragma unroll
    for (int n = 0; n < 4; ++n) acc[m][n] = (f32x4)0.0f;

  for (int kt = 0; kt < 256; kt += 64) {
    stage(kt);
    __syncthreads();

#pragma unroll
    for (int kk = 0; kk < 2; ++kk) {
      short8 af[4], bfr[4];
#pragma unroll
      for (int m = 0; m < 4; ++m) {
        const int row = wm * 64 + m * 16 + l15;
        const int xb  = (kk * 64 + kq * 16) ^ ((row & 7) << 4);
        af[m] = *(const short8*)(As + row * 128 + xb);
      }
#pragma unroll
      for (int n = 0; n < 4; ++n) {
        const int col = wn * 64 + n * 16 + l15;
        const int xb  = (kk * 64 + kq * 16) ^ ((col & 7) << 4);
        bfr[n] = *(const short8*)(Bs + col * 128 + xb);
      }
#pragma unroll
      for (int m = 0; m < 4; ++m)
#pragma unroll
        for (int n = 0; n < 4; ++n)
          acc[m][n] = __builtin_amdgcn_mfma_f32_16x16x32_bf16(af[m], bfr[n], acc[m][n], 0, 0, 0);
    }
    __syncthreads();
  }

  // ---- epilogue: v = acc + b_out + src ; LN1 ; write x_bf ----
#pragma unroll
  for (int n = 0; n < 4; ++n) {
    const int col = wn * 64 + n * 16 + l15;
    const float bv = b_out[col];
#pragma unroll
    for (int m = 0; m < 4; ++m)
#pragma unroll
      for (int j = 0; j < 4; ++j) {
        int row = bm * 128 + wm * 64 + m * 16 + kq * 4 + j;
        row = row < MROWS ? row : MROWS - 1;
        acc[m][n][j] += bv + src[(size_t)row * 256 + col];
      }
  }
  float s1[4][4], s2[4][4];
#pragma unroll
  for (int m = 0; m < 4; ++m)
#pragma unroll
    for (int j = 0; j < 4; ++j) {
      float a = 0.f, b = 0.f;
#pragma unroll
      for (int n = 0; n < 4; ++n) { const float v = acc[m][n][j]; a += v; b += v * v; }
      s1[m][j] = a; s2[m][j] = b;
    }
#pragma unroll
  for (int o = 1; o < 16; o <<= 1)
#pragma unroll
    for (int m = 0; m < 4; ++m)
#pragma unroll
      for (int j = 0; j < 4; ++j) {
        s1[m][j] += __shfl_xor(s1[m][j], o, 64);
        s2[m][j] += __shfl_xor(s2[m][j], o, 64);
      }
  if (l15 == 0)
#pragma unroll
    for (int m = 0; m < 4; ++m)
#pragma unroll
      for (int j = 0; j < 4; ++j)
        red[(wm * 64 + m * 16 + kq * 4 + j) * 4 + wn] = make_float2(s1[m][j], s2[m][j]);
  __syncthreads();
  float mean[4][4], rstd[4][4];
#pragma unroll
  for (int m = 0; m < 4; ++m)
#pragma unroll
    for (int j = 0; j < 4; ++j) {
      const int rl = wm * 64 + m * 16 + kq * 4 + j;
      float a = 0.f, b = 0.f;
#pragma unroll
      for (int w = 0; w < 4; ++w) { const float2 r = red[rl * 4 + w]; a += r.x; b += r.y; }
      const float mu = a * (1.0f / 256.0f);
      mean[m][j] = mu;
      rstd[m][j] = rsqrtf(b * (1.0f / 256.0f) - mu * mu + 1e-5f);
    }
#pragma unroll
  for (int n = 0; n < 4; ++n) {
    const int col = wn * 64 + n * 16 + l15;
    const float gg = g1[col], bb = be1[col];
#pragma unroll
    for (int m = 0; m < 4; ++m)
#pragma unroll
      for (int j = 0; j < 4; ++j) {
        const int row = bm * 128 + wm * 64 + m * 16 + kq * 4 + j;
        if (row < MROWS) {
          const float y = (acc[m][n][j] - mean[m][j]) * rstd[m][j] * gg + bb;
          x_bf[(size_t)row * 256 + col] = f2bf(y);
        }
      }
  }
}

// ---------------- fused FFN + LN2 (r9 v4 loop; residual from x_bf) ----------------
__global__ __launch_bounds__(1024, 2)
void ffn_ln2(const u16* __restrict__ x_bf, const u16* __restrict__ W1T,
             const u16* __restrict__ W2T, const float* __restrict__ b1,
             const float* __restrict__ b2,
             const float* __restrict__ g2, const float* __restrict__ be2,
             float* __restrict__ out)
{
  extern __shared__ char smem[];
  u16*  w1s = (u16*)(smem);            // [2][64][256]
  u16*  w2s = (u16*)(smem + 65536);    // [2][256][64]
  char* ps  = smem + 131072;           // [128][144B]
  float2* red = (float2*)(smem + 149504);  // [128][4]

  const int t    = threadIdx.x;
  const int lane = t & 63;
  const int wid  = t >> 6;             // 0..15
  const int l15  = lane & 15;
  const int kq   = lane >> 4;
  const int bm   = blockIdx.x;
  const int pwm  = wid >> 1, pwn = wid & 1;   // P: 8x2, tile 16x32
  const int vwm  = wid >> 2, vwn = wid & 3;   // PV: 4x4, tile 32x64

  short8 xr[8];
  {
    int ar = bm * 128 + pwm * 16 + l15;
    ar = ar < MROWS ? ar : MROWS - 1;
    const char* xb = (const char*)x_bf + (size_t)ar * 512 + kq * 16;
#pragma unroll
    for (int ks = 0; ks < 8; ++ks) xr[ks] = *(const short8*)(xb + ks * 64);
  }

  auto stage = [&](int buf, int it) {
#pragma unroll
    for (int i = 0; i < 2; ++i) {
      const int c  = i * 1024 + t;
      const int r1 = c >> 5;
      const int k1 = ((c & 31) ^ (r1 & 7)) * 8;
      async16(&W1T[(size_t)(it * 64 + r1) * 256 + k1], &w1s[buf * 16384 + c * 8]);
      const int r2 = c >> 3;
      const int k2 = ((c & 7) ^ (r2 & 7)) * 8;
      async16(&W2T[(size_t)r2 * 2048 + it * 64 + k2], &w2s[buf * 16384 + c * 8]);
    }
  };

  f32x4 acc[2][4];
#pragma unroll
  for (int m = 0; m < 2; ++m)
#pragma unroll
    for (int n = 0; n < 4; ++n) acc[m][n] = (f32x4)0.0f;

  stage(0, 0);
  __syncthreads();

  for (int it = 0; it < 32; ++it) {
    const int cur = it & 1;
    if (it < 31) stage(cur ^ 1, it + 1);

    f32x4 p[2];
    p[0] = (f32x4)0.0f; p[1] = (f32x4)0.0f;
#pragma unroll
    for (int ks = 0; ks < 8; ++ks) {
#pragma unroll
      for (int n = 0; n < 2; ++n) {
        const int wrow = pwn * 32 + n * 16 + l15;
        const int xb   = (((ks * 4 + kq) ^ (wrow & 7)) << 4);
        const short8 bfr = *(const short8*)((const char*)&w1s[cur * 16384] + wrow * 512 + xb);
        p[n] = __builtin_amdgcn_mfma_f32_16x16x32_bf16(xr[ks], bfr, p[n], 0, 0, 0);
      }
    }

#pragma unroll
    for (int n = 0; n < 2; ++n) {
      const int col = pwn * 32 + n * 16 + l15;
      const float bv = b1[it * 64 + col];
#pragma unroll
      for (int j = 0; j < 4; ++j) {
        const int prow = pwm * 16 + kq * 4 + j;
        *(u16*)(ps + prow * 144 + col * 2) = f2bf(fmaxf(p[n][j] + bv, 0.0f));
      }
    }
    __syncthreads();

#pragma unroll
    for (int kk = 0; kk < 2; ++kk) {
      short8 paf[2];
#pragma unroll
      for (int m = 0; m < 2; ++m) {
        const int arow = vwm * 32 + m * 16 + l15;
        paf[m] = *(const short8*)(ps + arow * 144 + (kk * 4 + kq) * 16);
      }
#pragma unroll
      for (int n = 0; n < 4; ++n) {
        const int brow = vwn * 64 + n * 16 + l15;
        const int xb   = (((kk * 4 + kq) ^ (brow & 7)) << 4);
        const short8 bfr = *(const short8*)((const char*)&w2s[cur * 16384] + brow * 128 + xb);
#pragma unroll
        for (int m = 0; m < 2; ++m)
          acc[m][n] = __builtin_amdgcn_mfma_f32_16x16x32_bf16(paf[m], bfr, acc[m][n], 0, 0, 0);
      }
    }
    __syncthreads();
  }

  // ---- epilogue: v = acc + b2 + x(bf16) ; LN2 ; write d_out ----
#pragma unroll
  for (int n = 0; n < 4; ++n) {
    const int col = vwn * 64 + n * 16 + l15;
    const float bv = b2[col];
#pragma unroll
    for (int m = 0; m < 2; ++m)
#pragma unroll
      for (int j = 0; j < 4; ++j) {
        int row = bm * 128 + vwm * 32 + m * 16 + kq * 4 + j;
        row = row < MROWS ? row : MROWS - 1;
        acc[m][n][j] += bv + bf2f(x_bf[(size_t)row * 256 + col]);
      }
  }
  float s1[2][4], s2[2][4];
#pragma unroll
  for (int m = 0; m < 2; ++m)
#pragma unroll
    for (int j = 0; j < 4; ++j) {
      float a = 0.f, b = 0.f;
#pragma unroll
      for (int n = 0; n < 4; ++n) { const float v = acc[m][n][j]; a += v; b += v * v; }
      s1[m][j] = a; s2[m][j] = b;
    }
#pragma unroll
  for (int o = 1; o < 16; o <<= 1)
#pragma unroll
    for (int m = 0; m < 2; ++m)
#pragma unroll
      for (int j = 0; j < 4; ++j) {
        s1[m][j] += __shfl_xor(s1[m][j], o, 64);
        s2[m][j] += __shfl_xor(s2[m][j], o, 64);
      }
  if (l15 == 0)
#pragma unroll
    for (int m = 0; m < 2; ++m)
#pragma unroll
      for (int j = 0; j < 4; ++j)
        red[(vwm * 32 + m * 16 + kq * 4 + j) * 4 + vwn] = make_float2(s1[m][j], s2[m][j]);
  __syncthreads();
  float mean[2][4], rstd[2][4];
#pragma unroll
  for (int m = 0; m < 2; ++m)
#pragma unroll
    for (int j = 0; j < 4; ++j) {
      const int rl = vwm * 32 + m * 16 + kq * 4 + j;
      float a = 0.f, b = 0.f;
#pragma unroll
      for (int w = 0; w < 4; ++w) { const float2 r = red[rl * 4 + w]; a += r.x; b += r.y; }
      const float mu = a * (1.0f / 256.0f);
      mean[m][j] = mu;
      rstd[m][j] = rsqrtf(b * (1.0f / 256.0f) - mu * mu + 1e-5f);
    }
#pragma unroll
  for (int n = 0; n < 4; ++n) {
    const int col = vwn * 64 + n * 16 + l15;
    const float gg = g2[col], bb = be2[col];
#pragma unroll
    for (int m = 0; m < 2; ++m)
#pragma unroll
      for (int j = 0; j < 4; ++j) {
        const int row = bm * 128 + vwm * 32 + m * 16 + kq * 4 + j;
        if (row < MROWS)
          out[(size_t)row * 256 + col] = (acc[m][n][j] - mean[m][j]) * rstd[m][j] * gg + bb;
      }
  }
}

// ---------------- MS-deform sampler v5: bf16 offattn input ----------------
__global__ __launch_bounds__(256)
void sampler_kernel(const u16* __restrict__ offattn,    // [M][384] bf16 (off 256 | attn 128)
                    const float* __restrict__ refp,     // [M][4][2]
                    const u16*  __restrict__ value,     // [M][256] bf16
                    u16*        __restrict__ src2)      // [M][256] bf16
{
  __shared__ float2 sWI[4][8][65];

  // bijective XCD-chunked swizzle: nwg=6647 = 7*831 + 830
  const int bid  = blockIdx.x;
  const int xcd  = bid & 7;
  const int idx  = bid >> 3;
  const int wg   = (xcd < 7) ? (xcd * 831 + idx) : (5817 + idx);

  const int t    = threadIdx.x;
  const int r4   = t >> 6;
  const int lane = t & 63;
  const int row  = wg * 4 + r4;
  const int b    = row / LQN;

  {
    const u16* oa = offattn + (size_t)row * 384;
    const float* rp = refp + (size_t)row * 8;
    const int p16 = lane & 15;
    const int l   = p16 >> 2;
    const int Wl  = (l == 0) ? 100 : (l == 1) ? 50 : (l == 2) ? 25 : 13;
    const int st  = (l == 0) ? 0 : (l == 1) ? 10000 : (l == 2) ? 12500 : 13125;
    const float rx = rp[l * 2 + 0] * (float)Wl - 0.5f;
    const float ry = rp[l * 2 + 1] * (float)Wl - 0.5f;

#pragma unroll
    for (int s = 0; s < 2; ++s) {
      const int h = s * 4 + (lane >> 4);
      float logit = bf2f(oa[256 + h * 16 + p16]);
      float mx = logit;
#pragma unroll
      for (int o = 1; o < 16; o <<= 1) mx = fmaxf(mx, __shfl_xor(mx, o, 64));
      float e = __expf(logit - mx);
      float ssum = e;
#pragma unroll
      for (int o = 1; o < 16; o <<= 1) ssum += __shfl_xor(ssum, o, 64);
      const float aw = e / ssum;

      const float ox = bf2f(oa[(h * 16 + p16) * 2 + 0]);
      const float oy = bf2f(oa[(h * 16 + p16) * 2 + 1]);
      const float gx = rx + ox;
      const float gy = ry + oy;
      const float x0f = floorf(gx), y0f = floorf(gy);
      const int   x0 = (int)x0f, y0 = (int)y0f;
      const float fx = gx - x0f, fy = gy - y0f;
#pragma unroll
      for (int c = 0; c < 4; ++c) {
        const int dx = c & 1, dy = c >> 1;
        const int xi = x0 + dx, yi = y0 + dy;
        const float wx = dx ? fx : 1.0f - fx;
        const float wy = dy ? fy : 1.0f - fy;
        const bool valid = (xi >= 0) && (xi < Wl) && (yi >= 0) && (yi < Wl);
        const int xc = min(max(xi, 0), Wl - 1);
        const int yc = min(max(yi, 0), Wl - 1);
        const int idxv = st + yc * Wl + xc;
        const float w = wx * wy * aw * (valid ? 1.0f : 0.0f);
        sWI[r4][h][p16 * 4 + c] = make_float2(w, __builtin_bit_cast(float, idxv));
      }
    }
  }
  __syncthreads();

  {
    const int e2 = lane >> 5;
    const int h  = (lane >> 2) & 7;
    const int c8 = lane & 3;
    const char* vbase = (const char*)value + (size_t)b * LQN * 512 + h * 64 + c8 * 16;
    const float2* wi = sWI[r4][h];

    float a[8];
#pragma unroll
    for (int i = 0; i < 8; ++i) a[i] = 0.f;

#pragma unroll 8
    for (int e = 0; e < 64; e += 2) {
      const float2 p = wi[e + e2];
      const float w  = p.x;
      const int  idxv = __builtin_bit_cast(int, p.y);
      const u32x4 u = *(const u32x4*)(vbase + (size_t)idxv * 512);
#pragma unroll
      for (int i = 0; i < 4; ++i) {
        a[2 * i]     += w * bf2f((u16)(u[i]));
        a[2 * i + 1] += w * bf2f((u16)(u[i] >> 16));
      }
    }
#pragma unroll
    for (int i = 0; i < 8; ++i) a[i] += __shfl_xor(a[i], 32, 64);

    if (e2 == 0) {
      u16 o[8];
#pragma unroll
      for (int i = 0; i < 8; ++i) o[i] = f2bf(a[i]);
      *(short8*)&src2[(size_t)row * 256 + h * 32 + c8 * 8] = *(short8*)o;
    }
  }
}

// ---------------- merged prep: qsrc (bid<6647) + weights (bid>=6647) ----------------
__global__ __launch_bounds__(256)
void prep_all(const float* __restrict__ src, const float* __restrict__ pos,
              u16* __restrict__ src_bf, u16* __restrict__ q_bf,
              const float* __restrict__ w_value, const float* __restrict__ w_off,
              const float* __restrict__ w_attn,  const float* __restrict__ w_out,
              const float* __restrict__ w_ffn1,  const float* __restrict__ w_ffn2,
              const float* __restrict__ b_off,   const float* __restrict__ b_attn,
              u16* __restrict__ WT_val, u16* __restrict__ WT_oa, u16* __restrict__ WT_out,
              u16* __restrict__ WT_f1,  u16* __restrict__ WT_f2, float* __restrict__ bias_oa)
{
  if (blockIdx.x < 6647) {
    const size_t i = (size_t)blockIdx.x * 256 + threadIdx.x;
    const f32x4 s = ((const f32x4*)src)[i];
    const f32x4 p = ((const f32x4*)pos)[i];
    u16x4 sb, qb;
#pragma unroll
    for (int j = 0; j < 4; ++j) { sb[j] = f2bf(s[j]); qb[j] = f2bf(s[j] + p[j]); }
    ((u16x4*)src_bf)[i] = sb;
    ((u16x4*)q_bf)[i]   = qb;
    return;
  }
  int i = (blockIdx.x - 6647) * 256 + threadIdx.x;
  if (i < 65536) {
    const int k = i >> 8, n = i & 255;
    WT_val[n * 256 + k] = f2bf(w_value[i]);
  } else if ((i -= 65536) < 65536) {
    const int k = i >> 8, n = i & 255;
    WT_oa[n * 256 + k] = f2bf(w_off[i]);
  } else if ((i -= 65536) < 32768) {
    const int k = i >> 7, n = i & 127;
    WT_oa[(256 + n) * 256 + k] = f2bf(w_attn[i]);
  } else if ((i -= 32768) < 65536) {
    const int k = i >> 8, n = i & 255;
    WT_out[n * 256 + k] = f2bf(w_out[i]);
  } else if ((i -= 65536) < 524288) {
    const int k = i >> 11, n = i & 2047;
    WT_f1[n * 256 + k] = f2bf(w_ffn1[i]);
  } else if ((i -= 524288) < 524288) {
    const int k = i >> 8, n = i & 255;
    WT_f2[n * 2048 + k] = f2bf(w_ffn2[i]);
  } else if ((i -= 524288) < 384) {
    bias_oa[i] = (i < 256) ? b_off[i] : b_attn[i - 256];
  }
}

// ---------------- launch ----------------
extern "C" void kernel_launch(void* const* d_in, const int* in_sizes, int n_in,
                              void* d_out, int out_size, void* d_ws, size_t ws_size,
                              hipStream_t stream)
{
  const float* src     = (const float*)d_in[0];
  const float* pos     = (const float*)d_in[1];
  const float* refp    = (const float*)d_in[2];
  const float* w_value = (const float*)d_in[3];
  const float* b_value = (const float*)d_in[4];
  const float* w_off   = (const float*)d_in[5];
  const float* b_off   = (const float*)d_in[6];
  const float* w_attn  = (const float*)d_in[7];
  const float* b_attn  = (const float*)d_in[8];
  const float* w_out   = (const float*)d_in[9];
  const float* b_out   = (const float*)d_in[10];
  const float* ln1_g   = (const float*)d_in[11];
  const float* ln1_b   = (const float*)d_in[12];
  const float* w_ffn1  = (const float*)d_in[13];
  const float* b_ffn1  = (const float*)d_in[14];
  const float* w_ffn2  = (const float*)d_in[15];
  const float* b_ffn2  = (const float*)d_in[16];
  const float* ln2_g   = (const float*)d_in[17];
  const float* ln2_b   = (const float*)d_in[18];

  char* ws = (char*)d_ws;
  size_t off = 0;
  auto alloc = [&](size_t bytes) { void* p = ws + off; off += (bytes + 255) & ~(size_t)255; return p; };

  u16*   src_bf   = (u16*)  alloc((size_t)MROWS * 256 * 2);
  u16*   q_bf     = (u16*)  alloc((size_t)MROWS * 256 * 2);   // later: x_bf
  u16*   offattn  = (u16*)  alloc((size_t)MROWS * 384 * 2);   // bf16
  u16*   value_bf = (u16*)  alloc((size_t)MROWS * 256 * 2);
  u16*   src2_bf  = (u16*)  alloc((size_t)MROWS * 256 * 2);
  u16*   WT_val   = (u16*)  alloc(256 * 256 * 2);
  u16*   WT_oa    = (u16*)  alloc(384 * 256 * 2);
  u16*   WT_out   = (u16*)  alloc(256 * 256 * 2);
  u16*   WT_f1    = (u16*)  alloc(2048 * 256 * 2);
  u16*   WT_f2    = (u16*)  alloc((size_t)256 * 2048 * 2);
  float* bias_oa  = (float*)alloc(384 * 4);

  u16* x_bf = q_bf;                  // alias (q_bf dead after gemm_dual)

  prep_all<<<6647 + 4994, 256, 0, stream>>>(src, pos, src_bf, q_bf,
                                            w_value, w_off, w_attn, w_out, w_ffn1, w_ffn2,
                                            b_off, b_attn,
                                            WT_val, WT_oa, WT_out, WT_f1, WT_f2, bias_oa);

  static bool attr_set = false;
  if (!attr_set) {
    hipFuncSetAttribute((const void*)ffn_ln2,
                        hipFuncAttributeMaxDynamicSharedMemorySize, 153600);
    hipFuncSetAttribute((const void*)outproj_ln1,
                        hipFuncAttributeMaxDynamicSharedMemorySize, 53248);
    attr_set = true;
  }

  // value-proj + off/attn-proj in one dispatch (both bf16 out)
  gemm_dual<<<dim3(208, 5), 256, 0, stream>>>(src_bf, WT_val, b_value, value_bf,
                                              q_bf, WT_oa, bias_oa, offattn);

  sampler_kernel<<<MROWS / 4, 256, 0, stream>>>(offattn, refp, value_bf, src2_bf);

  // out-proj + LN1 -> x_bf
  outproj_ln1<<<208, 512, 53248, stream>>>(src2_bf, WT_out, b_out, src,
                                           ln1_g, ln1_b, x_bf);

  // FFN + LN2 -> d_out (residual from x_bf)
  ffn_ln2<<<208, 1024, 153600, stream>>>(x_bf, WT_f1, WT_f2, b_ffn1, b_ffn2,
                                         ln2_g, ln2_b, (float*)d_out);
}